// Round 2
// baseline (995.684 us; speedup 1.0000x reference)
//
#include <hip/hip_runtime.h>

// WECT: weighted Euler characteristic transform.
// D=64 directions (lane = direction), H=256 heights, bins = [dir][height].
// LDS histogram layout is [height][dir] so bank = dir%32 -> 2-way (free).
// R1: U=8 unroll in vertex + simplex kernels for memory-level parallelism
// (R0 was latency-bound: VALUBusy 5.4%, HBM 4.7%, occupancy 35%).

#define HGT 256
#define NDIR 64
#define NBINS (HGT * NDIR)
#define U 8

__global__ void wect_maxnorm(const float* __restrict__ vc, int k0,
                             unsigned* __restrict__ maxbits) {
    float m = 0.f;
    for (int i = blockIdx.x * blockDim.x + threadIdx.x; i < k0;
         i += gridDim.x * blockDim.x) {
        float x = vc[3 * i], y = vc[3 * i + 1], z = vc[3 * i + 2];
        m = fmaxf(m, sqrtf(x * x + y * y + z * z));
    }
    for (int off = 32; off > 0; off >>= 1)
        m = fmaxf(m, __shfl_down(m, off, 64));
    __shared__ float sm[16];
    int wid = threadIdx.x >> 6, lane = threadIdx.x & 63;
    if (lane == 0) sm[wid] = m;
    __syncthreads();
    if (threadIdx.x == 0) {
        float b = sm[0];
        int nw = blockDim.x >> 6;
        for (int w = 1; w < nw; ++w) b = fmaxf(b, sm[w]);
        atomicMax(maxbits, __float_as_uint(b));  // valid: all values >= 0
    }
}

__device__ __forceinline__ int height_bin(float h, float mh, float inv) {
    int idx = (int)ceilf((255.0f * (mh + h)) * inv);
    return min(max(idx, 0), HGT - 1);
}

__global__ __launch_bounds__(512) void wect_vertex(
    const float* __restrict__ vc, const float* __restrict__ vw,
    const float* __restrict__ dirs, int k0,
    const unsigned* __restrict__ maxbits, unsigned char* __restrict__ vidx,
    float* __restrict__ out) {
    __shared__ float hist[NBINS];
    for (int i = threadIdx.x; i < NBINS; i += blockDim.x) hist[i] = 0.f;
    int lane = threadIdx.x & 63;
    float d0 = dirs[lane * 3], d1 = dirs[lane * 3 + 1], d2 = dirs[lane * 3 + 2];
    float mh = __uint_as_float(*maxbits);
    float inv = 1.0f / (2.0f * mh);
    __syncthreads();
    int wid = __builtin_amdgcn_readfirstlane(
        (blockIdx.x * blockDim.x + threadIdx.x) >> 6);
    int nw = (gridDim.x * blockDim.x) >> 6;
    int nchunks = k0 / U;  // full chunks
    for (int c = wid; c < nchunks; c += nw) {
        int base = c * U;
        float x[U], y[U], z[U], w[U];
#pragma unroll
        for (int j = 0; j < U; ++j) {
            x[j] = vc[3 * (base + j) + 0];
            y[j] = vc[3 * (base + j) + 1];
            z[j] = vc[3 * (base + j) + 2];
            w[j] = vw[base + j];
        }
        int idx[U];
#pragma unroll
        for (int j = 0; j < U; ++j) {
            float h = x[j] * d0 + y[j] * d1 + z[j] * d2;
            idx[j] = height_bin(h, mh, inv);
            vidx[(size_t)(base + j) * NDIR + lane] = (unsigned char)idx[j];
        }
#pragma unroll
        for (int j = 0; j < U; ++j)
            atomicAdd(&hist[idx[j] * NDIR + lane], w[j]);
    }
    // tail
    for (int k = nchunks * U + wid; k < k0; k += nw) {
        float h = vc[3 * k] * d0 + vc[3 * k + 1] * d1 + vc[3 * k + 2] * d2;
        int idx = height_bin(h, mh, inv);
        vidx[(size_t)k * NDIR + lane] = (unsigned char)idx;
        atomicAdd(&hist[idx * NDIR + lane], vw[k]);
    }
    __syncthreads();
    for (int i = threadIdx.x; i < NBINS; i += blockDim.x) {
        float v = hist[i];
        if (v != 0.f) atomicAdd(&out[(i & 63) * HGT + (i >> 6)], v);
    }
}

__global__ __launch_bounds__(512) void wect_simplex_idx(
    const int* __restrict__ edges, const float* __restrict__ ew,
    const int* __restrict__ tris, const float* __restrict__ tw, int k1, int k2,
    const unsigned char* __restrict__ vidx, float* __restrict__ out) {
    __shared__ float hist[NBINS];
    for (int i = threadIdx.x; i < NBINS; i += blockDim.x) hist[i] = 0.f;
    __syncthreads();
    int lane = threadIdx.x & 63;
    int wid = __builtin_amdgcn_readfirstlane(
        (blockIdx.x * blockDim.x + threadIdx.x) >> 6);
    int nw = (gridDim.x * blockDim.x) >> 6;

    // ---- edges: sign +1, max over 2 endpoints ----
    int echunks = k1 / U;
    for (int c = wid; c < echunks; c += nw) {
        int base = c * U;
        int2 e[U];
        float w[U];
#pragma unroll
        for (int j = 0; j < U; ++j) e[j] = ((const int2*)edges)[base + j];
#pragma unroll
        for (int j = 0; j < U; ++j) w[j] = ew[base + j];
        int a[U], b[U];
#pragma unroll
        for (int j = 0; j < U; ++j) {
            a[j] = vidx[(size_t)e[j].x * NDIR + lane];
            b[j] = vidx[(size_t)e[j].y * NDIR + lane];
        }
#pragma unroll
        for (int j = 0; j < U; ++j)
            atomicAdd(&hist[max(a[j], b[j]) * NDIR + lane], w[j]);
    }
    for (int s = echunks * U + wid; s < k1; s += nw) {
        int2 e = ((const int2*)edges)[s];
        int a = vidx[(size_t)e.x * NDIR + lane];
        int b = vidx[(size_t)e.y * NDIR + lane];
        atomicAdd(&hist[max(a, b) * NDIR + lane], ew[s]);
    }

    // ---- triangles: sign -1, max over 3 endpoints ----
    int tchunks = k2 / U;
    for (int c = wid; c < tchunks; c += nw) {
        int base = c * U;
        int v0[U], v1[U], v2[U];
        float w[U];
#pragma unroll
        for (int j = 0; j < U; ++j) {
            v0[j] = tris[3 * (base + j) + 0];
            v1[j] = tris[3 * (base + j) + 1];
            v2[j] = tris[3 * (base + j) + 2];
            w[j] = tw[base + j];
        }
        int a[U], b[U], cc[U];
#pragma unroll
        for (int j = 0; j < U; ++j) {
            a[j] = vidx[(size_t)v0[j] * NDIR + lane];
            b[j] = vidx[(size_t)v1[j] * NDIR + lane];
            cc[j] = vidx[(size_t)v2[j] * NDIR + lane];
        }
#pragma unroll
        for (int j = 0; j < U; ++j)
            atomicAdd(&hist[max(a[j], max(b[j], cc[j])) * NDIR + lane], -w[j]);
    }
    for (int s = tchunks * U + wid; s < k2; s += nw) {
        int v0 = tris[3 * s], v1 = tris[3 * s + 1], v2 = tris[3 * s + 2];
        int a = vidx[(size_t)v0 * NDIR + lane];
        int b = vidx[(size_t)v1 * NDIR + lane];
        int c = vidx[(size_t)v2 * NDIR + lane];
        atomicAdd(&hist[max(a, max(b, c)) * NDIR + lane], -tw[s]);
    }

    __syncthreads();
    for (int i = threadIdx.x; i < NBINS; i += blockDim.x) {
        float v = hist[i];
        if (v != 0.f) atomicAdd(&out[(i & 63) * HGT + (i >> 6)], v);
    }
}

// Fallback when ws is too small for the uint8 vidx table: recompute dots.
__global__ __launch_bounds__(512) void wect_simplex_rec(
    const int* __restrict__ edges, const float* __restrict__ ew,
    const int* __restrict__ tris, const float* __restrict__ tw, int k1, int k2,
    const float* __restrict__ vc, const float* __restrict__ dirs,
    const unsigned* __restrict__ maxbits, float* __restrict__ out) {
    __shared__ float hist[NBINS];
    for (int i = threadIdx.x; i < NBINS; i += blockDim.x) hist[i] = 0.f;
    int lane = threadIdx.x & 63;
    float d0 = dirs[lane * 3], d1 = dirs[lane * 3 + 1], d2 = dirs[lane * 3 + 2];
    float mh = __uint_as_float(*maxbits);
    float inv = 1.0f / (2.0f * mh);
    __syncthreads();
    int wid = (blockIdx.x * blockDim.x + threadIdx.x) >> 6;
    int nw = (gridDim.x * blockDim.x) >> 6;
    int total = k1 + k2;
    for (int s = wid; s < total; s += nw) {
        int idx;
        float w;
        if (s < k1) {
            int v0 = edges[2 * s], v1 = edges[2 * s + 1];
            float h0 = vc[3 * v0] * d0 + vc[3 * v0 + 1] * d1 + vc[3 * v0 + 2] * d2;
            float h1 = vc[3 * v1] * d0 + vc[3 * v1 + 1] * d1 + vc[3 * v1 + 2] * d2;
            idx = max(height_bin(h0, mh, inv), height_bin(h1, mh, inv));
            w = ew[s];
        } else {
            int t = s - k1;
            int v0 = tris[3 * t], v1 = tris[3 * t + 1], v2 = tris[3 * t + 2];
            float h0 = vc[3 * v0] * d0 + vc[3 * v0 + 1] * d1 + vc[3 * v0 + 2] * d2;
            float h1 = vc[3 * v1] * d0 + vc[3 * v1 + 1] * d1 + vc[3 * v1 + 2] * d2;
            float h2 = vc[3 * v2] * d0 + vc[3 * v2 + 1] * d1 + vc[3 * v2 + 2] * d2;
            idx = max(height_bin(h0, mh, inv),
                      max(height_bin(h1, mh, inv), height_bin(h2, mh, inv)));
            w = -tw[t];
        }
        atomicAdd(&hist[idx * NDIR + lane], w);
    }
    __syncthreads();
    for (int i = threadIdx.x; i < NBINS; i += blockDim.x) {
        float v = hist[i];
        if (v != 0.f) atomicAdd(&out[(i & 63) * HGT + (i >> 6)], v);
    }
}

__global__ void wect_cumsum(float* __restrict__ out) {
    // one wave (64 lanes) per direction row of 256 floats
    int lane = threadIdx.x;
    float4* row = (float4*)out + (size_t)blockIdx.x * 64;
    float4 v = row[lane];
    v.y += v.x;
    v.z += v.y;
    v.w += v.z;
    float s = v.w;
    float mine = s;
    for (int off = 1; off < 64; off <<= 1) {
        float t = __shfl_up(s, off, 64);
        if (lane >= off) s += t;
    }
    float excl = s - mine;
    v.x += excl;
    v.y += excl;
    v.z += excl;
    v.w += excl;
    row[lane] = v;
}

extern "C" void kernel_launch(void* const* d_in, const int* in_sizes, int n_in,
                              void* d_out, int out_size, void* d_ws,
                              size_t ws_size, hipStream_t stream) {
    const float* v_coords = (const float*)d_in[0];
    const float* v_weights = (const float*)d_in[1];
    const int* edges = (const int*)d_in[2];
    const float* e_weights = (const float*)d_in[3];
    const int* tris = (const int*)d_in[4];
    const float* t_weights = (const float*)d_in[5];
    const float* dirs = (const float*)d_in[6];
    // d_in[7] = num_heights (=256, hardcoded as HGT)

    int k0 = in_sizes[0] / 3;
    int k1 = in_sizes[2] / 2;
    int k2 = in_sizes[4] / 3;

    float* out = (float*)d_out;
    unsigned* maxbits = (unsigned*)d_ws;
    unsigned char* vidx = (unsigned char*)d_ws + 64;
    bool have_table = ws_size >= (size_t)k0 * NDIR + 64;

    hipMemsetAsync(d_ws, 0, 64, stream);
    hipMemsetAsync(d_out, 0, (size_t)NBINS * sizeof(float), stream);

    wect_maxnorm<<<256, 256, 0, stream>>>(v_coords, k0, maxbits);

    if (have_table) {
        wect_vertex<<<512, 512, 0, stream>>>(v_coords, v_weights, dirs, k0,
                                             maxbits, vidx, out);
        wect_simplex_idx<<<512, 512, 0, stream>>>(edges, e_weights, tris,
                                                  t_weights, k1, k2, vidx, out);
    } else {
        wect_simplex_rec<<<512, 512, 0, stream>>>(edges, e_weights, tris,
                                                  t_weights, k1, k2, v_coords,
                                                  dirs, maxbits, out);
    }
    wect_cumsum<<<NDIR, 64, 0, stream>>>(out);
}

// Round 4
// 785.768 us; speedup vs baseline: 1.2671x; 1.2671x over previous
//
#include <hip/hip_runtime.h>

// WECT: D=64 directions, H=256 heights. hist LDS layout [height][dir] (f32).
// vidx table: per vertex a 64-byte row; byte p holds the bin index for
// direction (p%4)*16 + p/4, so lane l's dword at offset (l&15)*4 carries
// dirs {c*16 + (l&15), c=0..3}. Gathers/stores are dword-coalesced.
// R3 = R2 with the flush fixed: global_atomic_pk_add_f32 doesn't assemble on
// gfx950 -> two scalar atomicAdds on contiguous [dir][height] addresses.

#define HGT 256
#define NDIR 64
#define NBINS (HGT * NDIR)
#define UV 4
#define UE 4
#define UT 4

__global__ void wect_maxnorm(const float* __restrict__ vc, int k0,
                             unsigned* __restrict__ maxbits) {
    float m = 0.f;
    for (int i = blockIdx.x * blockDim.x + threadIdx.x; i < k0;
         i += gridDim.x * blockDim.x) {
        float x = vc[3 * i], y = vc[3 * i + 1], z = vc[3 * i + 2];
        m = fmaxf(m, sqrtf(x * x + y * y + z * z));
    }
    for (int off = 32; off > 0; off >>= 1)
        m = fmaxf(m, __shfl_down(m, off, 64));
    __shared__ float sm[16];
    int wid = threadIdx.x >> 6, lane = threadIdx.x & 63;
    if (lane == 0) sm[wid] = m;
    __syncthreads();
    if (threadIdx.x == 0) {
        float b = sm[0];
        int nw = blockDim.x >> 6;
        for (int w = 1; w < nw; ++w) b = fmaxf(b, sm[w]);
        atomicMax(maxbits, __float_as_uint(b));  // valid: all values >= 0
    }
}

__device__ __forceinline__ int height_bin(float h, float mh, float inv) {
    int idx = (int)ceilf((255.0f * (mh + h)) * inv);
    return min(max(idx, 0), HGT - 1);
}

__device__ __forceinline__ void flush_hist(const float* hist,
                                           float* __restrict__ out) {
    int nthr = blockDim.x;
    for (int t = threadIdx.x; t < NBINS / 2; t += nthr) {
        int dir = t & 63;
        int p = (t >> 6) << 1;  // even height index
        float v0 = hist[p * 64 + dir];
        float v1 = hist[(p + 1) * 64 + dir];
        if (v0 != 0.f) atomicAdd(&out[dir * HGT + p], v0);
        if (v1 != 0.f) atomicAdd(&out[dir * HGT + p + 1], v1);
    }
}

__global__ __launch_bounds__(1024) void wect_vertex(
    const float* __restrict__ vc, const float* __restrict__ vw,
    const float* __restrict__ dirs, int k0,
    const unsigned* __restrict__ maxbits, unsigned* __restrict__ vidx4,
    float* __restrict__ out) {
    __shared__ float hist[NBINS];
    for (int i = threadIdx.x; i < NBINS; i += blockDim.x) hist[i] = 0.f;
    int lane = threadIdx.x & 63;
    int sub = lane & 15, g4 = lane >> 4;
    float dx[4], dy[4], dz[4];
#pragma unroll
    for (int c = 0; c < 4; ++c) {
        int d = c * 16 + sub;
        dx[c] = dirs[3 * d];
        dy[c] = dirs[3 * d + 1];
        dz[c] = dirs[3 * d + 2];
    }
    float mh = __uint_as_float(*maxbits);
    float inv = 1.0f / (2.0f * mh);
    __syncthreads();
    int wid = __builtin_amdgcn_readfirstlane(
        (blockIdx.x * blockDim.x + threadIdx.x) >> 6);
    int nw = (gridDim.x * blockDim.x) >> 6;
    int G = k0 >> 2;  // groups of 4 vertices
    for (int gb = wid * UV; gb < G; gb += nw * UV) {
        float x[UV], y[UV], z[UV], w[UV];
        int kk[UV];
#pragma unroll
        for (int j = 0; j < UV; ++j) {
            int g = min(gb + j, G - 1);
            int k = g * 4 + g4;
            kk[j] = k;
            x[j] = vc[3 * k];
            y[j] = vc[3 * k + 1];
            z[j] = vc[3 * k + 2];
            w[j] = vw[k];
        }
#pragma unroll
        for (int j = 0; j < UV; ++j) {
            if (gb + j >= G) break;
            unsigned pack = 0;
            int idx[4];
#pragma unroll
            for (int c = 0; c < 4; ++c) {
                float h = x[j] * dx[c] + y[j] * dy[c] + z[j] * dz[c];
                idx[c] = height_bin(h, mh, inv);
                pack |= (unsigned)idx[c] << (8 * c);
            }
            vidx4[kk[j] * 16 + sub] = pack;
#pragma unroll
            for (int c = 0; c < 4; ++c)
                atomicAdd(&hist[idx[c] * 64 + c * 16 + sub], w[j]);
        }
    }
    // tail (k0 % 4): one lane-group handles each leftover vertex
    for (int k = (k0 & ~3); k < k0; ++k) {
        if (g4 == (k & 3)) {
            float xx = vc[3 * k], yy = vc[3 * k + 1], zz = vc[3 * k + 2];
            float ww = vw[k];
            unsigned pack = 0;
#pragma unroll
            for (int c = 0; c < 4; ++c) {
                float h = xx * dx[c] + yy * dy[c] + zz * dz[c];
                int idx = height_bin(h, mh, inv);
                pack |= (unsigned)idx << (8 * c);
                if (wid == 0) atomicAdd(&hist[idx * 64 + c * 16 + sub], ww);
            }
            if (wid == 0) vidx4[k * 16 + sub] = pack;
        }
    }
    __syncthreads();
    flush_hist(hist, out);
}

__global__ __launch_bounds__(1024) void wect_simplex(
    const int* __restrict__ edges, const float* __restrict__ ew,
    const int* __restrict__ tris, const float* __restrict__ tw, int k1, int k2,
    const unsigned* __restrict__ vidx4, float* __restrict__ out) {
    __shared__ float hist[NBINS];
    for (int i = threadIdx.x; i < NBINS; i += blockDim.x) hist[i] = 0.f;
    __syncthreads();
    int lane = threadIdx.x & 63;
    int sub = lane & 15, g4 = lane >> 4;
    int wid = __builtin_amdgcn_readfirstlane(
        (blockIdx.x * blockDim.x + threadIdx.x) >> 6);
    int nw = (gridDim.x * blockDim.x) >> 6;

    // ---- edges: +w, max over 2 endpoints ----
    int GE = k1 >> 2;
    for (int gb = wid * UE; gb < GE; gb += nw * UE) {
        unsigned a[UE], b[UE];
        float w[UE];
#pragma unroll
        for (int j = 0; j < UE; ++j) {
            int g = min(gb + j, GE - 1);
            int e = g * 4 + g4;
            int2 ev = ((const int2*)edges)[e];
            w[j] = ew[e];
            a[j] = vidx4[(size_t)ev.x * 16 + sub];
            b[j] = vidx4[(size_t)ev.y * 16 + sub];
        }
#pragma unroll
        for (int j = 0; j < UE; ++j) {
            if (gb + j >= GE) break;
#pragma unroll
            for (int c = 0; c < 4; ++c) {
                int ia = (a[j] >> (8 * c)) & 255;
                int ib = (b[j] >> (8 * c)) & 255;
                int m = max(ia, ib);
                atomicAdd(&hist[m * 64 + c * 16 + sub], w[j]);
            }
        }
    }
    for (int e = (k1 & ~3); e < k1; ++e) {  // tail: one lane-group per edge
        if (wid == 0 && g4 == (e & 3)) {
            int2 ev = ((const int2*)edges)[e];
            float w = ew[e];
            unsigned a = vidx4[(size_t)ev.x * 16 + sub];
            unsigned b = vidx4[(size_t)ev.y * 16 + sub];
#pragma unroll
            for (int c = 0; c < 4; ++c) {
                int m = max((int)((a >> (8 * c)) & 255),
                            (int)((b >> (8 * c)) & 255));
                atomicAdd(&hist[m * 64 + c * 16 + sub], w);
            }
        }
    }

    // ---- triangles: -w, max over 3 endpoints ----
    int GT = k2 >> 2;
    for (int gb = wid * UT; gb < GT; gb += nw * UT) {
        unsigned a[UT], b[UT], cc[UT];
        float w[UT];
#pragma unroll
        for (int j = 0; j < UT; ++j) {
            int g = min(gb + j, GT - 1);
            int t = g * 4 + g4;
            int i0 = tris[3 * t], i1 = tris[3 * t + 1], i2 = tris[3 * t + 2];
            w[j] = tw[t];
            a[j] = vidx4[(size_t)i0 * 16 + sub];
            b[j] = vidx4[(size_t)i1 * 16 + sub];
            cc[j] = vidx4[(size_t)i2 * 16 + sub];
        }
#pragma unroll
        for (int j = 0; j < UT; ++j) {
            if (gb + j >= GT) break;
#pragma unroll
            for (int c = 0; c < 4; ++c) {
                int ia = (a[j] >> (8 * c)) & 255;
                int ib = (b[j] >> (8 * c)) & 255;
                int ic = (cc[j] >> (8 * c)) & 255;
                int m = max(ia, max(ib, ic));
                atomicAdd(&hist[m * 64 + c * 16 + sub], -w[j]);
            }
        }
    }
    for (int t = (k2 & ~3); t < k2; ++t) {  // tail
        if (wid == 0 && g4 == (t & 3)) {
            int i0 = tris[3 * t], i1 = tris[3 * t + 1], i2 = tris[3 * t + 2];
            float w = tw[t];
            unsigned a = vidx4[(size_t)i0 * 16 + sub];
            unsigned b = vidx4[(size_t)i1 * 16 + sub];
            unsigned cv = vidx4[(size_t)i2 * 16 + sub];
#pragma unroll
            for (int c = 0; c < 4; ++c) {
                int m = max((int)((a >> (8 * c)) & 255),
                            max((int)((b >> (8 * c)) & 255),
                                (int)((cv >> (8 * c)) & 255)));
                atomicAdd(&hist[m * 64 + c * 16 + sub], -w);
            }
        }
    }

    __syncthreads();
    flush_hist(hist, out);
}

// Fallback when ws is too small for the vidx table: recompute dots (slow).
__global__ __launch_bounds__(512) void wect_simplex_rec(
    const int* __restrict__ edges, const float* __restrict__ ew,
    const int* __restrict__ tris, const float* __restrict__ tw, int k1, int k2,
    const float* __restrict__ vc, const float* __restrict__ dirs,
    const unsigned* __restrict__ maxbits, float* __restrict__ out) {
    __shared__ float hist[NBINS];
    for (int i = threadIdx.x; i < NBINS; i += blockDim.x) hist[i] = 0.f;
    int lane = threadIdx.x & 63;
    float d0 = dirs[lane * 3], d1 = dirs[lane * 3 + 1], d2 = dirs[lane * 3 + 2];
    float mh = __uint_as_float(*maxbits);
    float inv = 1.0f / (2.0f * mh);
    __syncthreads();
    int wid = (blockIdx.x * blockDim.x + threadIdx.x) >> 6;
    int nw = (gridDim.x * blockDim.x) >> 6;
    int total = k1 + k2;
    for (int s = wid; s < total; s += nw) {
        int idx;
        float w;
        if (s < k1) {
            int v0 = edges[2 * s], v1 = edges[2 * s + 1];
            float h0 = vc[3 * v0] * d0 + vc[3 * v0 + 1] * d1 + vc[3 * v0 + 2] * d2;
            float h1 = vc[3 * v1] * d0 + vc[3 * v1 + 1] * d1 + vc[3 * v1 + 2] * d2;
            idx = max(height_bin(h0, mh, inv), height_bin(h1, mh, inv));
            w = ew[s];
        } else {
            int t = s - k1;
            int v0 = tris[3 * t], v1 = tris[3 * t + 1], v2 = tris[3 * t + 2];
            float h0 = vc[3 * v0] * d0 + vc[3 * v0 + 1] * d1 + vc[3 * v0 + 2] * d2;
            float h1 = vc[3 * v1] * d0 + vc[3 * v1 + 1] * d1 + vc[3 * v1 + 2] * d2;
            float h2 = vc[3 * v2] * d0 + vc[3 * v2 + 1] * d1 + vc[3 * v2 + 2] * d2;
            idx = max(height_bin(h0, mh, inv),
                      max(height_bin(h1, mh, inv), height_bin(h2, mh, inv)));
            w = -tw[t];
        }
        atomicAdd(&hist[idx * NDIR + lane], w);
    }
    __syncthreads();
    for (int i = threadIdx.x; i < NBINS; i += blockDim.x) {
        float v = hist[i];
        if (v != 0.f) atomicAdd(&out[(i & 63) * HGT + (i >> 6)], v);
    }
}

// Vertex fallback (no table store), lane = dir, unpermuted.
__global__ __launch_bounds__(512) void wect_vertex_rec(
    const float* __restrict__ vc, const float* __restrict__ vw,
    const float* __restrict__ dirs, int k0,
    const unsigned* __restrict__ maxbits, float* __restrict__ out) {
    __shared__ float hist[NBINS];
    for (int i = threadIdx.x; i < NBINS; i += blockDim.x) hist[i] = 0.f;
    int lane = threadIdx.x & 63;
    float d0 = dirs[lane * 3], d1 = dirs[lane * 3 + 1], d2 = dirs[lane * 3 + 2];
    float mh = __uint_as_float(*maxbits);
    float inv = 1.0f / (2.0f * mh);
    __syncthreads();
    int wid = (blockIdx.x * blockDim.x + threadIdx.x) >> 6;
    int nw = (gridDim.x * blockDim.x) >> 6;
    for (int k = wid; k < k0; k += nw) {
        float h = vc[3 * k] * d0 + vc[3 * k + 1] * d1 + vc[3 * k + 2] * d2;
        int idx = height_bin(h, mh, inv);
        atomicAdd(&hist[idx * NDIR + lane], vw[k]);
    }
    __syncthreads();
    for (int i = threadIdx.x; i < NBINS; i += blockDim.x) {
        float v = hist[i];
        if (v != 0.f) atomicAdd(&out[(i & 63) * HGT + (i >> 6)], v);
    }
}

__global__ void wect_cumsum(float* __restrict__ out) {
    // one wave (64 lanes) per direction row of 256 floats
    int lane = threadIdx.x;
    float4* row = (float4*)out + (size_t)blockIdx.x * 64;
    float4 v = row[lane];
    v.y += v.x;
    v.z += v.y;
    v.w += v.z;
    float s = v.w;
    float mine = s;
    for (int off = 1; off < 64; off <<= 1) {
        float t = __shfl_up(s, off, 64);
        if (lane >= off) s += t;
    }
    float excl = s - mine;
    v.x += excl;
    v.y += excl;
    v.z += excl;
    v.w += excl;
    row[lane] = v;
}

extern "C" void kernel_launch(void* const* d_in, const int* in_sizes, int n_in,
                              void* d_out, int out_size, void* d_ws,
                              size_t ws_size, hipStream_t stream) {
    const float* v_coords = (const float*)d_in[0];
    const float* v_weights = (const float*)d_in[1];
    const int* edges = (const int*)d_in[2];
    const float* e_weights = (const float*)d_in[3];
    const int* tris = (const int*)d_in[4];
    const float* t_weights = (const float*)d_in[5];
    const float* dirs = (const float*)d_in[6];
    // d_in[7] = num_heights (=256, hardcoded as HGT)

    int k0 = in_sizes[0] / 3;
    int k1 = in_sizes[2] / 2;
    int k2 = in_sizes[4] / 3;

    float* out = (float*)d_out;
    unsigned* maxbits = (unsigned*)d_ws;
    unsigned* vidx4 = (unsigned*)((char*)d_ws + 64);
    bool have_table = ws_size >= (size_t)k0 * NDIR + 64;

    (void)hipMemsetAsync(d_ws, 0, 64, stream);
    (void)hipMemsetAsync(d_out, 0, (size_t)NBINS * sizeof(float), stream);

    wect_maxnorm<<<256, 256, 0, stream>>>(v_coords, k0, maxbits);

    if (have_table) {
        wect_vertex<<<256, 1024, 0, stream>>>(v_coords, v_weights, dirs, k0,
                                              maxbits, vidx4, out);
        wect_simplex<<<256, 1024, 0, stream>>>(edges, e_weights, tris,
                                               t_weights, k1, k2, vidx4, out);
    } else {
        wect_vertex_rec<<<512, 512, 0, stream>>>(v_coords, v_weights, dirs, k0,
                                                 maxbits, out);
        wect_simplex_rec<<<512, 512, 0, stream>>>(edges, e_weights, tris,
                                                  t_weights, k1, k2, v_coords,
                                                  dirs, maxbits, out);
    }
    wect_cumsum<<<NDIR, 64, 0, stream>>>(out);
}

// Round 5
// 411.760 us; speedup vs baseline: 2.4181x; 1.9083x over previous
//
#include <hip/hip_runtime.h>

// WECT, direction-major (R4). 64 dirs = 16 groups x 4 dirs.
// tableT[g][v] : dword of 4 packed u8 height bins for dirs g*4..g*4+3.
// Per-group table = 800KB -> L2-resident per XCD (g = bid&15 pins groups
// g and g+8 to XCD g&7 under round-robin block->XCD dispatch).
// Lane = vertex/simplex -> independent 4B gathers, U=4 unroll for MLP.
// Wave-private LDS hists (8 x 4KB = 32KB) -> no cross-wave atomic pileups.
// (R3 was latency-bound: ~5 outstanding CL/CU, VALUBusy 2.3%, occ 42%.)

#define HGT 256
#define NDIR 64
#define NBINS (HGT * NDIR)
#define NG 16
#define SLICES 64
#define TPB 512
#define NWAVE (TPB / 64)

__global__ void wect_maxnorm(const float* __restrict__ vc, int k0,
                             unsigned* __restrict__ maxbits) {
    float m = 0.f;
    for (int i = blockIdx.x * blockDim.x + threadIdx.x; i < k0;
         i += gridDim.x * blockDim.x) {
        float x = vc[3 * i], y = vc[3 * i + 1], z = vc[3 * i + 2];
        m = fmaxf(m, sqrtf(x * x + y * y + z * z));
    }
    for (int off = 32; off > 0; off >>= 1)
        m = fmaxf(m, __shfl_down(m, off, 64));
    __shared__ float sm[16];
    int wid = threadIdx.x >> 6, lane = threadIdx.x & 63;
    if (lane == 0) sm[wid] = m;
    __syncthreads();
    if (threadIdx.x == 0) {
        float b = sm[0];
        int nw = blockDim.x >> 6;
        for (int w = 1; w < nw; ++w) b = fmaxf(b, sm[w]);
        atomicMax(maxbits, __float_as_uint(b));  // valid: all values >= 0
    }
}

__device__ __forceinline__ int height_bin(float h, float mh, float inv) {
    int idx = (int)ceilf((255.0f * (mh + h)) * inv);
    return min(max(idx, 0), HGT - 1);
}

// ---------------- direction-major kernels ----------------

__global__ __launch_bounds__(TPB, 6) void wect_vertex_dm(
    const float* __restrict__ vc, const float* __restrict__ vw,
    const float* __restrict__ dirs, int k0,
    const unsigned* __restrict__ maxbits, unsigned* __restrict__ tableT,
    float* __restrict__ out) {
    __shared__ float hist[NWAVE][1024];
    int tid = threadIdx.x, wv = tid >> 6;
    for (int t = tid; t < NWAVE * 1024; t += TPB) ((float*)hist)[t] = 0.f;
    int g = blockIdx.x & (NG - 1);
    int slice = blockIdx.x >> 4;
    float dx[4], dy[4], dz[4];
#pragma unroll
    for (int c = 0; c < 4; ++c) {
        int d = g * 4 + c;
        dx[c] = dirs[3 * d];
        dy[c] = dirs[3 * d + 1];
        dz[c] = dirs[3 * d + 2];
    }
    float mh = __uint_as_float(*maxbits);
    float inv = 1.0f / (2.0f * mh);
    unsigned* tab = tableT + (size_t)g * k0;
    __syncthreads();
    int lo = (int)((long long)k0 * slice / SLICES);
    int hi = (int)((long long)k0 * (slice + 1) / SLICES);
    for (int i = lo + tid; i < hi; i += TPB) {
        float x = vc[3 * i], y = vc[3 * i + 1], z = vc[3 * i + 2];
        float w = vw[i];
        unsigned pack = 0;
#pragma unroll
        for (int c = 0; c < 4; ++c) {
            float h = x * dx[c] + y * dy[c] + z * dz[c];
            int b = height_bin(h, mh, inv);
            pack |= (unsigned)b << (8 * c);
            atomicAdd(&hist[wv][c * 256 + b], w);
        }
        tab[i] = pack;
    }
    __syncthreads();
    for (int t = tid; t < 1024; t += TPB) {
        float s = 0.f;
#pragma unroll
        for (int u = 0; u < NWAVE; ++u) s += hist[u][t];
        if (s != 0.f) atomicAdd(&out[(g * 4 + (t >> 8)) * HGT + (t & 255)], s);
    }
}

__global__ __launch_bounds__(TPB, 6) void wect_simplex_dm(
    const int2* __restrict__ edges, const float* __restrict__ ew,
    const int* __restrict__ tris, const float* __restrict__ tw, int k1, int k2,
    const unsigned* __restrict__ tableT, int k0, float* __restrict__ out) {
    __shared__ float hist[NWAVE][1024];
    int tid = threadIdx.x, wv = tid >> 6;
    for (int t = tid; t < NWAVE * 1024; t += TPB) ((float*)hist)[t] = 0.f;
    int g = blockIdx.x & (NG - 1);
    int slice = blockIdx.x >> 4;
    const unsigned* tab = tableT + (size_t)g * k0;
    __syncthreads();

    // ---- edges: +w, max over 2 endpoints ----
    {
        int lo = (int)((long long)k1 * slice / SLICES);
        int hi = (int)((long long)k1 * (slice + 1) / SLICES);
        for (int base = lo + tid; base < hi; base += TPB * 4) {
            int ii[4];
            int2 ev[4];
            float w[4];
#pragma unroll
            for (int j = 0; j < 4; ++j) {
                ii[j] = base + j * TPB;
                if (ii[j] < hi) {
                    ev[j] = edges[ii[j]];
                    w[j] = ew[ii[j]];
                }
            }
            unsigned pa[4], pb[4];
#pragma unroll
            for (int j = 0; j < 4; ++j)
                if (ii[j] < hi) {
                    pa[j] = tab[ev[j].x];
                    pb[j] = tab[ev[j].y];
                }
#pragma unroll
            for (int j = 0; j < 4; ++j)
                if (ii[j] < hi) {
#pragma unroll
                    for (int c = 0; c < 4; ++c) {
                        int m = max((int)((pa[j] >> (8 * c)) & 255),
                                    (int)((pb[j] >> (8 * c)) & 255));
                        atomicAdd(&hist[wv][c * 256 + m], w[j]);
                    }
                }
        }
    }

    // ---- triangles: -w, max over 3 endpoints ----
    {
        int lo = (int)((long long)k2 * slice / SLICES);
        int hi = (int)((long long)k2 * (slice + 1) / SLICES);
        for (int base = lo + tid; base < hi; base += TPB * 4) {
            int ii[4];
            int v0[4], v1[4], v2[4];
            float w[4];
#pragma unroll
            for (int j = 0; j < 4; ++j) {
                ii[j] = base + j * TPB;
                if (ii[j] < hi) {
                    v0[j] = tris[3 * ii[j]];
                    v1[j] = tris[3 * ii[j] + 1];
                    v2[j] = tris[3 * ii[j] + 2];
                    w[j] = tw[ii[j]];
                }
            }
            unsigned pa[4], pb[4], pc[4];
#pragma unroll
            for (int j = 0; j < 4; ++j)
                if (ii[j] < hi) {
                    pa[j] = tab[v0[j]];
                    pb[j] = tab[v1[j]];
                    pc[j] = tab[v2[j]];
                }
#pragma unroll
            for (int j = 0; j < 4; ++j)
                if (ii[j] < hi) {
#pragma unroll
                    for (int c = 0; c < 4; ++c) {
                        int m = max((int)((pa[j] >> (8 * c)) & 255),
                                    max((int)((pb[j] >> (8 * c)) & 255),
                                        (int)((pc[j] >> (8 * c)) & 255)));
                        atomicAdd(&hist[wv][c * 256 + m], -w[j]);
                    }
                }
        }
    }

    __syncthreads();
    for (int t = tid; t < 1024; t += TPB) {
        float s = 0.f;
#pragma unroll
        for (int u = 0; u < NWAVE; ++u) s += hist[u][t];
        if (s != 0.f) atomicAdd(&out[(g * 4 + (t >> 8)) * HGT + (t & 255)], s);
    }
}

// ---------------- fallback kernels (no workspace table) ----------------

__global__ __launch_bounds__(512) void wect_simplex_rec(
    const int* __restrict__ edges, const float* __restrict__ ew,
    const int* __restrict__ tris, const float* __restrict__ tw, int k1, int k2,
    const float* __restrict__ vc, const float* __restrict__ dirs,
    const unsigned* __restrict__ maxbits, float* __restrict__ out) {
    __shared__ float hist[NBINS];
    for (int i = threadIdx.x; i < NBINS; i += blockDim.x) hist[i] = 0.f;
    int lane = threadIdx.x & 63;
    float d0 = dirs[lane * 3], d1 = dirs[lane * 3 + 1], d2 = dirs[lane * 3 + 2];
    float mh = __uint_as_float(*maxbits);
    float inv = 1.0f / (2.0f * mh);
    __syncthreads();
    int wid = (blockIdx.x * blockDim.x + threadIdx.x) >> 6;
    int nw = (gridDim.x * blockDim.x) >> 6;
    int total = k1 + k2;
    for (int s = wid; s < total; s += nw) {
        int idx;
        float w;
        if (s < k1) {
            int v0 = edges[2 * s], v1 = edges[2 * s + 1];
            float h0 = vc[3 * v0] * d0 + vc[3 * v0 + 1] * d1 + vc[3 * v0 + 2] * d2;
            float h1 = vc[3 * v1] * d0 + vc[3 * v1 + 1] * d1 + vc[3 * v1 + 2] * d2;
            idx = max(height_bin(h0, mh, inv), height_bin(h1, mh, inv));
            w = ew[s];
        } else {
            int t = s - k1;
            int v0 = tris[3 * t], v1 = tris[3 * t + 1], v2 = tris[3 * t + 2];
            float h0 = vc[3 * v0] * d0 + vc[3 * v0 + 1] * d1 + vc[3 * v0 + 2] * d2;
            float h1 = vc[3 * v1] * d0 + vc[3 * v1 + 1] * d1 + vc[3 * v1 + 2] * d2;
            float h2 = vc[3 * v2] * d0 + vc[3 * v2 + 1] * d1 + vc[3 * v2 + 2] * d2;
            idx = max(height_bin(h0, mh, inv),
                      max(height_bin(h1, mh, inv), height_bin(h2, mh, inv)));
            w = -tw[t];
        }
        atomicAdd(&hist[idx * NDIR + lane], w);
    }
    __syncthreads();
    for (int i = threadIdx.x; i < NBINS; i += blockDim.x) {
        float v = hist[i];
        if (v != 0.f) atomicAdd(&out[(i & 63) * HGT + (i >> 6)], v);
    }
}

__global__ __launch_bounds__(512) void wect_vertex_rec(
    const float* __restrict__ vc, const float* __restrict__ vw,
    const float* __restrict__ dirs, int k0,
    const unsigned* __restrict__ maxbits, float* __restrict__ out) {
    __shared__ float hist[NBINS];
    for (int i = threadIdx.x; i < NBINS; i += blockDim.x) hist[i] = 0.f;
    int lane = threadIdx.x & 63;
    float d0 = dirs[lane * 3], d1 = dirs[lane * 3 + 1], d2 = dirs[lane * 3 + 2];
    float mh = __uint_as_float(*maxbits);
    float inv = 1.0f / (2.0f * mh);
    __syncthreads();
    int wid = (blockIdx.x * blockDim.x + threadIdx.x) >> 6;
    int nw = (gridDim.x * blockDim.x) >> 6;
    for (int k = wid; k < k0; k += nw) {
        float h = vc[3 * k] * d0 + vc[3 * k + 1] * d1 + vc[3 * k + 2] * d2;
        int idx = height_bin(h, mh, inv);
        atomicAdd(&hist[idx * NDIR + lane], vw[k]);
    }
    __syncthreads();
    for (int i = threadIdx.x; i < NBINS; i += blockDim.x) {
        float v = hist[i];
        if (v != 0.f) atomicAdd(&out[(i & 63) * HGT + (i >> 6)], v);
    }
}

__global__ void wect_cumsum(float* __restrict__ out) {
    // one wave (64 lanes) per direction row of 256 floats
    int lane = threadIdx.x;
    float4* row = (float4*)out + (size_t)blockIdx.x * 64;
    float4 v = row[lane];
    v.y += v.x;
    v.z += v.y;
    v.w += v.z;
    float s = v.w;
    float mine = s;
    for (int off = 1; off < 64; off <<= 1) {
        float t = __shfl_up(s, off, 64);
        if (lane >= off) s += t;
    }
    float excl = s - mine;
    v.x += excl;
    v.y += excl;
    v.z += excl;
    v.w += excl;
    row[lane] = v;
}

extern "C" void kernel_launch(void* const* d_in, const int* in_sizes, int n_in,
                              void* d_out, int out_size, void* d_ws,
                              size_t ws_size, hipStream_t stream) {
    const float* v_coords = (const float*)d_in[0];
    const float* v_weights = (const float*)d_in[1];
    const int* edges = (const int*)d_in[2];
    const float* e_weights = (const float*)d_in[3];
    const int* tris = (const int*)d_in[4];
    const float* t_weights = (const float*)d_in[5];
    const float* dirs = (const float*)d_in[6];
    // d_in[7] = num_heights (=256, hardcoded as HGT)

    int k0 = in_sizes[0] / 3;
    int k1 = in_sizes[2] / 2;
    int k2 = in_sizes[4] / 3;

    float* out = (float*)d_out;
    unsigned* maxbits = (unsigned*)d_ws;
    unsigned* tableT = (unsigned*)((char*)d_ws + 64);
    bool have_table = ws_size >= 64 + (size_t)NG * k0 * 4;

    (void)hipMemsetAsync(d_ws, 0, 64, stream);
    (void)hipMemsetAsync(d_out, 0, (size_t)NBINS * sizeof(float), stream);

    wect_maxnorm<<<256, 256, 0, stream>>>(v_coords, k0, maxbits);

    if (have_table) {
        wect_vertex_dm<<<NG * SLICES, TPB, 0, stream>>>(
            v_coords, v_weights, dirs, k0, maxbits, tableT, out);
        wect_simplex_dm<<<NG * SLICES, TPB, 0, stream>>>(
            (const int2*)edges, e_weights, tris, t_weights, k1, k2, tableT, k0,
            out);
    } else {
        wect_vertex_rec<<<512, 512, 0, stream>>>(v_coords, v_weights, dirs, k0,
                                                 maxbits, out);
        wect_simplex_rec<<<512, 512, 0, stream>>>(edges, e_weights, tris,
                                                  t_weights, k1, k2, v_coords,
                                                  dirs, maxbits, out);
    }
    wect_cumsum<<<NDIR, 64, 0, stream>>>(out);
}